// Round 6
// baseline (92.716 us; speedup 1.0000x reference)
//
#include <hip/hip_runtime.h>
#include <cfloat>
#include <cstdint>

#define BB    4              // batches
#define NN    8192           // points per cloud
#define NT    8              // rows (gt queries) per thread
#define TPB   256            // threads per block
#define NTILE (NT*TPB)       // 2048 rows per block
#define NBQ   (NN/NTILE)     // 4 row-tiles
#define MSL   64             // pred points (cols) per slice
#define LSL   2              // col slices per block -> 128 cols/block
#define CPB   (LSL*MSL)      // 128 cols per block
#define MS    (NN/CPB)       // 64 col superslices
#define NPAIR (MSL/2)        // 32 col-pairs per slice
#define NHW   (TPB/32)       // 8 half-waves per block
#define NBLK  (NBQ*MS*BB)    // 1024 blocks total

static __device__ __forceinline__ float vmin3(float a, float b, float c) {
    float r;
    asm("v_min3_f32 %0, %1, %2, %3" : "=v"(r) : "v"(a), "v"(b), "v"(c));
    return r;
}
static __device__ __forceinline__ float vmin2(float a, float b) {
    float r;
    asm("v_min_f32 %0, %1, %2" : "=v"(r) : "v"(a), "v"(b));
    return r;
}

// order-preserving float<->uint mapping (finite floats)
__device__ __forceinline__ unsigned mapf(float f) {
    unsigned b = __float_as_uint(f);
    return b ^ ((unsigned)((int)b >> 31) | 0x80000000u);
}
__device__ __forceinline__ float unmapf(unsigned u) {
    unsigned b = u ^ (((u & 0x80000000u) != 0u) ? 0x80000000u : 0xFFFFFFFFu);
    return __uint_as_float(b);
}

// ws layout: [0, BB*NN)        row mins (mapped uint)
//            [BB*NN, 2*BB*NN)  col mins (mapped uint)
//            [2*BB*NN]         ticket counter
__global__ __launch_bounds__(TPB) void chamfer_onepass_kernel(
    const float* __restrict__ pred, const float* __restrict__ gt,
    const float* __restrict__ coords, unsigned* __restrict__ ws,
    float* __restrict__ out)
{
    const int b  = blockIdx.y;
    const int nb = blockIdx.x & (NBQ - 1);
    const int ms = blockIdx.x >> 2;          // 0..63
    const size_t base = (size_t)b * 3 * NN;
    const float* gr = gt     + base;
    const float* pr = pred   + base;
    const float* cc = coords + base;

    __shared__ float4 tileE[LSL][NPAIR];     // col 2j   : (-2x,-2y,-2z,|q|^2)
    __shared__ float4 tileO[LSL][NPAIR];     // col 2j+1
    __shared__ float  colmin[NHW][CPB];      // per-half-wave col partial mins

    const int tid = threadIdx.x;

    // stage both col slices (threads 0..127, coalesced-ish)
    if (tid < CPB) {
        int m   = ms * CPB + tid;
        float x = cc[m]        + pr[m];
        float y = cc[NN + m]   + pr[NN + m];
        float z = cc[2*NN + m] + pr[2*NN + m];
        float4 v = make_float4(-2.f*x, -2.f*y, -2.f*z, fmaf(x, x, fmaf(y, y, z*z)));
        int s = tid >> 6, j = tid & (MSL - 1);
        if (j & 1) tileO[s][j >> 1] = v; else tileE[s][j >> 1] = v;
    }
    for (int j = tid; j < NHW * CPB; j += TPB) (&colmin[0][0])[j] = FLT_MAX;

    // gt rows in registers
    float px[NT], py[NT], pz[NT], sqn[NT], mv[NT];
    const int n0 = nb * NTILE + tid;
    #pragma unroll
    for (int k = 0; k < NT; ++k) {
        int n   = n0 + k * TPB;
        float x = cc[n]        + gr[n];
        float y = cc[NN + n]   + gr[NN + n];
        float z = cc[2*NN + n] + gr[2*NN + n];
        px[k] = x; py[k] = y; pz[k] = z;
        sqn[k] = fmaf(x, x, fmaf(y, y, z*z));
        mv[k]  = FLT_MAX;
    }
    __syncthreads();

    const int ll = tid & 31;
    float* cmbase = colmin[tid >> 5];

    #pragma unroll
    for (int s = 0; s < LSL; ++s) {
        float* cm = cmbase + s * MSL;
        int jp = ll;
        float4 a = tileE[s][jp];
        float4 c = tileO[s][jp];
        #pragma unroll 2
        for (int i = 0; i < NPAIR; ++i) {
            const int jn = (jp + 1) & (NPAIR - 1);
            float4 an = tileE[s][jn];
            float4 cn = tileO[s][jn];
            float d0[NT], d1[NT];
            #pragma unroll
            for (int k = 0; k < NT; ++k) {
                float w0 = a.w + sqn[k];
                float w1 = c.w + sqn[k];
                d0[k] = fmaf(px[k], a.x, fmaf(py[k], a.y, fmaf(pz[k], a.z, w0)));
                d1[k] = fmaf(px[k], c.x, fmaf(py[k], c.y, fmaf(pz[k], c.z, w1)));
                mv[k] = vmin3(mv[k], d0[k], d1[k]);
            }
            float t0 = vmin3(d0[0], d0[1], d0[2]);
            float u0 = vmin3(d0[3], d0[4], d0[5]);
            float s0 = vmin3(d0[6], d0[7], t0);
            float c0 = vmin2(s0, u0);
            float t1 = vmin3(d1[0], d1[1], d1[2]);
            float u1 = vmin3(d1[3], d1[4], d1[5]);
            float s1 = vmin3(d1[6], d1[7], t1);
            float c1 = vmin2(s1, u1);
            float2* slot = (float2*)&cm[2 * jp];
            float2 old = *slot;
            old.x = vmin2(old.x, c0);
            old.y = vmin2(old.y, c1);
            *slot = old;
            jp = jn; a = an; c = cn;
        }
    }

    // dist1 row mins -> global atomics
    unsigned* wsrow = ws + (size_t)b * NN;
    #pragma unroll
    for (int k = 0; k < NT; ++k)
        atomicMin(&wsrow[n0 + k * TPB], mapf(mv[k]));

    __syncthreads();
    // dist2 col mins: combine 8 half-wave arrays, one atomic per col
    unsigned* wscol = ws + (size_t)BB * NN + (size_t)b * NN;
    if (tid < CPB) {
        float v = vmin3(colmin[0][tid], colmin[1][tid], colmin[2][tid]);
        v = vmin3(v, colmin[3][tid], colmin[4][tid]);
        v = vmin3(v, colmin[5][tid], colmin[6][tid]);
        v = vmin2(v, colmin[7][tid]);
        atomicMin(&wscol[ms * CPB + tid], mapf(v));
    }

    // ---- last-block final reduction (device-scope fence + ticket) ----
    __threadfence();
    __shared__ int lastf;
    if (tid == 0) {
        unsigned t = atomicAdd(&ws[2 * BB * NN], 1u);
        lastf = (t == (unsigned)(NBLK - 1));
    }
    __syncthreads();
    if (lastf) {
        __threadfence();                     // acquire: see all blocks' mins
        const uint4* p = (const uint4*)ws;   // 16384 uint4 = rows+cols
        float ssum = 0.0f;
        #pragma unroll 4
        for (int t = 0; t < (2 * BB * NN / 4) / TPB; ++t) {  // 64 iters
            uint4 u = p[tid + t * TPB];
            ssum += (unmapf(u.x) + unmapf(u.y)) + (unmapf(u.z) + unmapf(u.w));
        }
        #pragma unroll
        for (int off = 32; off > 0; off >>= 1)
            ssum += __shfl_down(ssum, off);
        __shared__ float sm[4];
        if ((tid & 63) == 0) sm[tid >> 6] = ssum;
        __syncthreads();
        if (tid == 0) out[0] = ((sm[0] + sm[1]) + (sm[2] + sm[3])) * (1.0f / (float)BB);
    }
}

// init mins to +inf (mapped 0xFFFFFFFF) and ticket counter to 0
__global__ __launch_bounds__(256) void ws_init_kernel(unsigned* __restrict__ ws)
{
    ((uint4*)ws)[blockIdx.x * 256 + threadIdx.x] = make_uint4(~0u, ~0u, ~0u, ~0u);
    if (blockIdx.x == 0 && threadIdx.x == 0) ws[2 * BB * NN] = 0u;
}

extern "C" void kernel_launch(void* const* d_in, const int* in_sizes, int n_in,
                              void* d_out, int out_size, void* d_ws, size_t ws_size,
                              hipStream_t stream) {
    const float* pred   = (const float*)d_in[0];
    const float* gt     = (const float*)d_in[1];
    const float* coords = (const float*)d_in[2];
    unsigned*    wsu    = (unsigned*)d_ws;
    float*       out    = (float*)d_out;

    ws_init_kernel<<<64, 256, 0, stream>>>(wsu);
    dim3 grid(NBQ * MS, BB);                   // 256 x 4 = 1024 blocks
    chamfer_onepass_kernel<<<grid, TPB, 0, stream>>>(pred, gt, coords, wsu, out);
}

// Round 7
// 45.278 us; speedup vs baseline: 2.0477x; 2.0477x over previous
//
#include <hip/hip_runtime.h>
#include <cfloat>
#include <cstdint>

#define BB    4              // batches
#define NN    8192           // points per cloud
#define NT    8              // rows (gt queries) per thread
#define TPB   256            // threads per block
#define NTILE (NT*TPB)       // 2048 rows per block
#define NBQ   (NN/NTILE)     // 4 row-tiles
#define CPB   64             // cols (pred points) per block == ring size
#define MS    (NN/CPB)       // 128 col slices

static __device__ __forceinline__ float vmin3(float a, float b, float c) {
    float r;
    asm("v_min3_f32 %0, %1, %2, %3" : "=v"(r) : "v"(a), "v"(b), "v"(c));
    return r;
}
static __device__ __forceinline__ float vmin2(float a, float b) {
    float r;
    asm("v_min_f32 %0, %1, %2" : "=v"(r) : "v"(a), "v"(b));
    return r;
}

// order-preserving float<->uint mapping (finite floats)
__device__ __forceinline__ unsigned mapf(float f) {
    unsigned b = __float_as_uint(f);
    return b ^ ((unsigned)((int)b >> 31) | 0x80000000u);
}
__device__ __forceinline__ float unmapf(unsigned u) {
    unsigned b = u ^ (((u & 0x80000000u) != 0u) ? 0x80000000u : 0xFFFFFFFFu);
    return __uint_as_float(b);
}

// One pass over the distance matrix. Block: 2048 rows (regs) x 64 cols (LDS).
// Rows: min in registers. Cols: 1 col/lane rotating ring — the col partial
// travels lane-to-lane via __shfl (no LDS RMW, no colmin arrays). Lane l
// processes col (l+i)&63 at iter i; after 64 iters lane l holds the full
// wave partial for col (l+63)&63 -> one global atomicMin per lane.
__global__ __launch_bounds__(TPB, 6) void chamfer_onepass_kernel(
    const float* __restrict__ pred, const float* __restrict__ gt,
    const float* __restrict__ coords, unsigned* __restrict__ ws)
{
    const int b  = blockIdx.y;
    const int nb = blockIdx.x & (NBQ - 1);
    const int ms = blockIdx.x >> 2;          // 0..127
    const size_t base = (size_t)b * 3 * NN;
    const float* gr = gt     + base;
    const float* pr = pred   + base;
    const float* cc = coords + base;

    __shared__ float4 tile[CPB];             // (-2x,-2y,-2z,|q|^2) per pred point

    const int tid = threadIdx.x;

    // stage pred slice (threads 0..63)
    if (tid < CPB) {
        int m   = ms * CPB + tid;
        float x = cc[m]        + pr[m];
        float y = cc[NN + m]   + pr[NN + m];
        float z = cc[2*NN + m] + pr[2*NN + m];
        tile[tid] = make_float4(-2.f*x, -2.f*y, -2.f*z, fmaf(x, x, fmaf(y, y, z*z)));
    }

    // gt rows in registers
    float px[NT], py[NT], pz[NT], sqn[NT], mv[NT];
    const int n0 = nb * NTILE + tid;
    #pragma unroll
    for (int k = 0; k < NT; ++k) {
        int n   = n0 + k * TPB;
        float x = cc[n]        + gr[n];
        float y = cc[NN + n]   + gr[NN + n];
        float z = cc[2*NN + n] + gr[2*NN + n];
        px[k] = x; py[k] = y; pz[k] = z;
        sqn[k] = fmaf(x, x, fmaf(y, y, z*z));
        mv[k]  = FLT_MAX;
    }
    __syncthreads();

    const int lane = tid & 63;
    const int nxt  = (lane + 1) & 63;        // shfl source (hoisted)
    float cm = FLT_MAX;                      // traveling col partial

    int jp = lane;
    float4 q = tile[jp];
    #pragma unroll 2
    for (int i = 0; i < CPB; ++i) {
        const int jn = (jp + 1) & (CPB - 1);
        float4 qn = tile[jn];                // prefetch next col
        float d[NT];
        #pragma unroll
        for (int k = 0; k < NT; ++k) {
            d[k]  = fmaf(px[k], q.x, fmaf(py[k], q.y, fmaf(pz[k], q.z, q.w + sqn[k])));
            mv[k] = vmin2(mv[k], d[k]);
        }
        // 8 -> 1 col tree for this (lane, col)
        float t = vmin3(d[0], d[1], d[2]);
        float u = vmin3(d[3], d[4], d[5]);
        float s = vmin3(d[6], d[7], t);
        float c = vmin2(s, u);
        // pass the partial to the lane that processes this col next iter
        cm = vmin2(__shfl(cm, nxt), c);
        jp = jn; q = qn;
    }

    // dist1: row mins -> global atomics
    unsigned* wsrow = ws + (size_t)b * NN;
    #pragma unroll
    for (int k = 0; k < NT; ++k)
        atomicMin(&wsrow[n0 + k * TPB], mapf(mv[k]));

    // dist2: per-wave col partial -> global atomic (4 per col per block)
    unsigned* wscol = ws + (size_t)BB * NN + (size_t)b * NN;
    const int cidx = (lane + CPB - 1) & (CPB - 1);
    atomicMin(&wscol[ms * CPB + cidx], mapf(cm));
}

// init mins to +inf in mapped-uint space (0xFFFFFFFF), 16384 uint4 stores
__global__ __launch_bounds__(256) void ws_init_kernel(unsigned* __restrict__ ws)
{
    ((uint4*)ws)[blockIdx.x * 256 + threadIdx.x] = make_uint4(~0u, ~0u, ~0u, ~0u);
}

// stage A: 64 blocks x 256 threads, uint4 per thread -> 64 partials
__global__ __launch_bounds__(256) void chamfer_reduce_a(
    const unsigned* __restrict__ ws, float* __restrict__ partial)
{
    int idx = blockIdx.x * 256 + threadIdx.x;
    const uint4* p = (const uint4*)ws;
    uint4 u = p[idx];
    float s = (unmapf(u.x) + unmapf(u.y)) + (unmapf(u.z) + unmapf(u.w));
    #pragma unroll
    for (int off = 32; off > 0; off >>= 1)
        s += __shfl_down(s, off);
    __shared__ float sm[4];
    if ((threadIdx.x & 63) == 0) sm[threadIdx.x >> 6] = s;
    __syncthreads();
    if (threadIdx.x == 0)
        partial[blockIdx.x] = (sm[0] + sm[1]) + (sm[2] + sm[3]);
}

__global__ __launch_bounds__(64) void chamfer_reduce_b(
    const float* __restrict__ partial, float* __restrict__ out)
{
    float s = partial[threadIdx.x];
    #pragma unroll
    for (int off = 32; off > 0; off >>= 1)
        s += __shfl_down(s, off);
    if (threadIdx.x == 0) out[0] = s * (1.0f / (float)BB);
}

extern "C" void kernel_launch(void* const* d_in, const int* in_sizes, int n_in,
                              void* d_out, int out_size, void* d_ws, size_t ws_size,
                              hipStream_t stream) {
    const float* pred   = (const float*)d_in[0];
    const float* gt     = (const float*)d_in[1];
    const float* coords = (const float*)d_in[2];
    unsigned*    wsu    = (unsigned*)d_ws;     // 2*B*N uints = 256 KB
    float*       part   = (float*)((char*)d_ws + (size_t)2 * BB * NN * sizeof(unsigned));
    float*       out    = (float*)d_out;

    ws_init_kernel<<<64, 256, 0, stream>>>(wsu);
    dim3 grid(NBQ * MS, BB);                   // 512 x 4 = 2048 blocks
    chamfer_onepass_kernel<<<grid, TPB, 0, stream>>>(pred, gt, coords, wsu);
    chamfer_reduce_a<<<64, 256, 0, stream>>>(wsu, part);
    chamfer_reduce_b<<<1, 64, 0, stream>>>(part, out);
}